// Round 1
// baseline (189.284 us; speedup 1.0000x reference)
//
#include <hip/hip_runtime.h>
#include <hip/hip_bf16.h>
#include <stdint.h>

#define T_TOKENS 8192
#define D_DIM    1024
#define NE       10
#define NT       8
#define SEG      2048   // padded per-expert list capacity (actual ~1638+-40)

typedef unsigned short u16;
typedef __attribute__((ext_vector_type(8))) __bf16 bf16x8;
typedef __attribute__((ext_vector_type(4))) float  f32x4;
typedef __attribute__((ext_vector_type(8))) unsigned short u16x8;
typedef __attribute__((ext_vector_type(4))) unsigned short u16x4;

static __device__ __forceinline__ u16 f32_to_bf16(float f) {
  union { float f; uint32_t u; } v; v.f = f;
  uint32_t u = v.u;
  return (u16)((u + 0x7fffu + ((u >> 16) & 1u)) >> 16);
}
static __device__ __forceinline__ float bf16_to_f32(u16 u) {
  union { uint32_t u; float f; } v; v.u = ((uint32_t)u) << 16; return v.f;
}

// async 16B global->LDS DMA; LDS dest = wave-uniform base + lane*16 [m97/m104]
static __device__ __forceinline__ void async_load16(const u16* g, u16* l) {
  __builtin_amdgcn_global_load_lds(
      (const __attribute__((address_space(1))) void*)(const void*)g,
      (__attribute__((address_space(3))) void*)(void*)l, 16, 0, 0);
}

// ---------------------------------------------------------------------------
// Kernel 1: prep = gate + weight-transpose fused in one dispatch (they're
// independent; fusing removes a launch gap and overlaps two BW-bound
// phases). blockIdx.x < 512 -> gate role (16 tokens/block); else transpose
// role (64x64 fp32->bf16 transpose tile). LDS is a union (41 KB).
// Gate: fp32 logits -> softmax -> top-2 (strict > scan = lax.top_k
// lower-index tie-break) -> normalized true weights; bf16 x; combined
// per-expert token lists (token appears <=1x per expert); reverse index+
// weight per (token,slot) for combine.
// ---------------------------------------------------------------------------
union PrepShared {
  struct { float gws[NE * D_DIM]; float gbs[NE]; int se[32]; float swt[32]; } g;
  struct { float tile[64][65]; } t;
};

__global__ __launch_bounds__(256) void prep_kernel(
    const float* __restrict__ x, const float* __restrict__ gw,
    const float* __restrict__ gb, const float* __restrict__ W,
    u16* __restrict__ xb, u16* __restrict__ wT,
    int* __restrict__ cnt, int* __restrict__ tokList,
    int* __restrict__ revIdx, float* __restrict__ revW) {
  __shared__ PrepShared sh;
  int tid = threadIdx.x;

  if (blockIdx.x >= 512) {
    // ---- transpose role: W [e][d][j] fp32 -> wT [e][j][d] bf16 ----
    int tb = blockIdx.x - 512;
    int e  = tb >> 8;
    int rem = tb & 255;
    int k0 = (rem >> 4) * 64;
    int n0 = (rem & 15) * 64;
    int c  = tid & 63;
    int r0 = tid >> 6;
    const float* We = W + ((size_t)e << 20);
#pragma unroll
    for (int rr = 0; rr < 16; ++rr) {
      int r = rr * 4 + r0;
      sh.t.tile[c][r] = We[(size_t)(k0 + r) * 1024 + n0 + c];
    }
    __syncthreads();
    u16* wTe = wT + ((size_t)e << 20);
#pragma unroll
    for (int rr = 0; rr < 16; ++rr) {
      int n = rr * 4 + r0;
      wTe[(size_t)(n0 + n) * 1024 + k0 + c] = f32_to_bf16(sh.t.tile[n][c]);
    }
    return;
  }

  // ---- gate role ----
  {
    const f32x4* g4 = (const f32x4*)gw;
    f32x4* s4 = (f32x4*)sh.g.gws;
    for (int i = tid; i < NE * D_DIM / 4; i += 256) s4[i] = g4[i];
  }
  if (tid < NE) sh.g.gbs[tid] = gb[tid];
  __syncthreads();
  int lane = tid & 63;
  int wv   = tid >> 6;
  const f32x4* gws4 = (const f32x4*)sh.g.gws;
  for (int it = 0; it < 4; ++it) {
    int slot = wv * 4 + it;
    int t = blockIdx.x * 16 + slot;
    const f32x4* xr4 = (const f32x4*)(x + (size_t)t * D_DIM);
    f32x4 xv[4];
#pragma unroll
    for (int jj = 0; jj < 4; ++jj) xv[jj] = xr4[lane + 64 * jj];
    u16x4* xbr = (u16x4*)(xb + (size_t)t * D_DIM);
#pragma unroll
    for (int jj = 0; jj < 4; ++jj) {
      u16x4 pk;
#pragma unroll
      for (int k = 0; k < 4; ++k) pk[k] = f32_to_bf16(xv[jj][k]);
      xbr[lane + 64 * jj] = pk;
    }
    float logit[NE];
#pragma unroll
    for (int e = 0; e < NE; ++e) {
      float a = 0.f;
#pragma unroll
      for (int jj = 0; jj < 4; ++jj) {
        f32x4 gv = gws4[e * 256 + lane + 64 * jj];
#pragma unroll
        for (int k = 0; k < 4; ++k) a = fmaf(xv[jj][k], gv[k], a);
      }
#pragma unroll
      for (int off = 32; off >= 1; off >>= 1) a += __shfl_xor(a, off);
      logit[e] = a + sh.g.gbs[e];
    }
    float mx = logit[0];
#pragma unroll
    for (int e = 1; e < NE; ++e) mx = fmaxf(mx, logit[e]);
    float p[NE]; float s = 0.f;
#pragma unroll
    for (int e = 0; e < NE; ++e) { p[e] = expf(logit[e] - mx); s += p[e]; }
    int e0 = 0; float b0 = p[0];
#pragma unroll
    for (int e = 1; e < NE; ++e) if (p[e] > b0) { b0 = p[e]; e0 = e; }
    int e1 = -1; float b1 = -1.f;
#pragma unroll
    for (int e = 0; e < NE; ++e) if (e != e0 && p[e] > b1) { b1 = p[e]; e1 = e; }
    float w0 = b0 / s, w1 = b1 / s;
    float tw0 = (e0 < NT) ? w0 : 0.f;
    float tw1 = (e1 < NT) ? w1 : 0.f;
    float denom = tw0 + tw1;
    float nw0 = 0.f, nw1 = 0.f;
    if (denom > 0.f) { nw0 = tw0 / denom; nw1 = tw1 / denom; }
    if (lane == 0) {
      sh.g.se[slot * 2]     = (e0 < NT) ? e0 : -1;  sh.g.swt[slot * 2]     = nw0;
      sh.g.se[slot * 2 + 1] = (e1 < NT) ? e1 : -1;  sh.g.swt[slot * 2 + 1] = nw1;
      if (e0 >= NT) { revIdx[t * 2]     = -1; revW[t * 2]     = 0.f; }
      if (e1 >= NT) { revIdx[t * 2 + 1] = -1; revW[t * 2 + 1] = 0.f; }
    }
  }
  __syncthreads();
  // compaction: thread e<8 scans 32 (token,slot) entries; one padded atomic.
  if (tid < NT) {
    int e = tid, c = 0;
    for (int i = 0; i < 32; ++i) c += (sh.g.se[i] == e);
    if (c > 0) {
      int base = atomicAdd(&cnt[e * 32], c);
      int j = 0;
      for (int i = 0; i < 32; ++i) {
        if (sh.g.se[i] == e) {
          int tt  = blockIdx.x * 16 + (i >> 1);
          int pos = base + j;
          tokList[e * SEG + pos]   = tt;
          revIdx[tt * 2 + (i & 1)] = e * SEG + pos;
          revW[tt * 2 + (i & 1)]   = sh.g.swt[i];
          ++j;
        }
      }
    }
  }
}

// ---------------------------------------------------------------------------
// Kernel 2: per-expert gathered GEMM. grid x=expert (XCD-affine: expert e's
// blocks -> XCD e, so its 2MB B + ~3.3MB gathered A stay L2-resident).
// 128x128 tile, BK=32, 4 waves x 4x4 mfma_f32_16x16x32_bf16.
// R6 changes (R5 measured 56.7us @ MfmaUtil 19%, VALU 13%, HBM 13%,
// BANK_CONFLICT 3.47M -> latency/sync-bound, nothing saturated):
//  (a) XOR swizzle period 4 -> 8 rows: old kcd=kcp^(rl&3) gave even rows in
//      any 8-lane service group only 2 distinct chunks (start bank
//      (row&1)*16+chunk*4) => 2-way conflict on every ds_read_b128. New
//      kcd=kcp^((rl>>1)&3): 8 consecutive lanes start at banks
//      {0,16,4,20,8,24,12,28}, each lane's 4 dwords tile all 32 banks once.
//  (b) ONE barrier per K-step (was 2): order [vmcnt(4)][lgkmcnt(0)]
//      [s_barrier][issue kt+2][read kt][MFMA]. The barrier now proves both
//      hazards at once: every wave confirmed its tile-kt DMAs landed BEFORE
//      the barrier (so post-barrier reads are safe cross-wave), and every
//      wave's iter-(kt-1) ds_reads are drained (lgkmcnt 0) BEFORE the
//      barrier (so the post-barrier DMA into slot (kt+2)%3 == (kt-1)%3
//      cannot race them). Ring stays 3-slot/48KB -> 3 blocks/CU preserved;
//      miss coverage stays ~2 iterations (issue at kt, consumed at kt+2).
//  (c) nontemporal ybuf stores: 27MB of streaming writes were thrashing the
//      per-XCD L2 (working set 5.3MB vs 4MB, DMA hit 93%).
// Epilogue: raw (acc+bias) -> bf16 ybuf, plain stores, no races.
// ---------------------------------------------------------------------------
__global__ __launch_bounds__(256) void moe_gemm(
    const u16* __restrict__ xb, const u16* __restrict__ wT,
    const int* __restrict__ cnt, const int* __restrict__ tokList,
    const float* __restrict__ eb, u16* __restrict__ ybuf) {
  int e  = blockIdx.x;
  int c  = cnt[e * 32];
  int m0 = blockIdx.z * 128;
  if (m0 >= c) return;
  int n0 = blockIdx.y * 128;
  __shared__ __align__(16) u16 As[3][128 * 32];
  __shared__ __align__(16) u16 Bs[3][128 * 32];
  __shared__ int tokS[128];
  int tid = threadIdx.x;
  if (tid < 128) {
    int gm = m0 + tid;
    tokS[tid] = (gm < c) ? tokList[e * SEG + gm] : tokList[e * SEG];
  }
  __syncthreads();
  int lane = tid & 63;
  int wv   = tid >> 6;
  // staging: wave wv covers rows [wv*32, wv*32+32); lane -> (row, chunk)
  int rl  = lane >> 2;             // 0..15
  int kcp = lane & 3;              // physical chunk slot
  int kcd = kcp ^ ((rl >> 1) & 3); // data chunk fetched (8-row XOR swizzle)
  int rowL0 = wv * 32 + rl, rowL1 = rowL0 + 16;
  const u16* gA0 = xb + (size_t)tokS[rowL0] * 1024 + kcd * 8;
  const u16* gA1 = xb + (size_t)tokS[rowL1] * 1024 + kcd * 8;
  const u16* wTe = wT + ((size_t)e << 20);
  const u16* gB0 = wTe + (size_t)(n0 + rowL0) * 1024 + kcd * 8;
  const u16* gB1 = wTe + (size_t)(n0 + rowL1) * 1024 + kcd * 8;
  int ldsA0 = (wv * 32) * 32, ldsA1 = (wv * 32 + 16) * 32;

  int wm = wv >> 1, wn = wv & 1;
  int lrow = lane & 15;
  int q    = lane >> 4;
  int sw   = (q ^ ((lrow >> 1) & 3)) * 8;   // matches 8-row write swizzle
  f32x4 acc[4][4];
#pragma unroll
  for (int i = 0; i < 4; ++i)
#pragma unroll
    for (int j = 0; j < 4; ++j) acc[i][j] = (f32x4){0.f, 0.f, 0.f, 0.f};

  // prologue: tiles 0,1 -> slots 0,1 (8 loads in flight)
#pragma unroll
  for (int p = 0; p < 2; ++p) {
    int ko = p * 32;
    async_load16(gA0 + ko, As[p] + ldsA0);
    async_load16(gA1 + ko, As[p] + ldsA1);
    async_load16(gB0 + ko, Bs[p] + ldsA0);
    async_load16(gB1 + ko, Bs[p] + ldsA1);
  }

  int cur = 0;                       // slot of tile kt (kt % 3)
  for (int kt = 0; kt < 32; ++kt) {
    // confirm tile kt landed: outstanding = tiles {kt, kt+1} = 8 DMAs;
    // wait to <=4 leaves only tile kt+1 in flight. Last iter drains fully.
    if (kt < 31) {
      asm volatile("s_waitcnt vmcnt(4)" ::: "memory");
    } else {
      asm volatile("s_waitcnt vmcnt(0)" ::: "memory");
    }
    // all of this wave's iter-(kt-1) ds_reads delivered -> slot (kt-1)%3
    // is dead data for this wave; the barrier makes that true block-wide.
    asm volatile("s_waitcnt lgkmcnt(0)" ::: "memory");
    asm volatile("s_barrier" ::: "memory");
    if (kt < 30) {
      int st = cur - 1; if (st < 0) st += 3;   // (kt+2) % 3
      int ko = (kt + 2) * 32;
      async_load16(gA0 + ko, As[st] + ldsA0);
      async_load16(gA1 + ko, As[st] + ldsA1);
      async_load16(gB0 + ko, Bs[st] + ldsA0);
      async_load16(gB1 + ko, Bs[st] + ldsA1);
    }
    bf16x8 af[4], bfr[4];
#pragma unroll
    for (int mt = 0; mt < 4; ++mt)
      af[mt] = *(const bf16x8*)(As[cur] + (wm * 64 + mt * 16 + lrow) * 32 + sw);
#pragma unroll
    for (int nt = 0; nt < 4; ++nt)
      bfr[nt] = *(const bf16x8*)(Bs[cur] + (wn * 64 + nt * 16 + lrow) * 32 + sw);
#pragma unroll
    for (int mt = 0; mt < 4; ++mt)
#pragma unroll
      for (int nt = 0; nt < 4; ++nt)
        acc[mt][nt] = __builtin_amdgcn_mfma_f32_16x16x32_bf16(
            af[mt], bfr[nt], acc[mt][nt], 0, 0, 0);
    ++cur; if (cur == 3) cur = 0;
  }
  // epilogue: C/D layout col=lane&15, row=(lane>>4)*4+reg [m89]
  int rq = lane >> 4;
  float bias[4];
#pragma unroll
  for (int nt = 0; nt < 4; ++nt)
    bias[nt] = eb[e * 1024 + n0 + wn * 64 + nt * 16 + lrow];
  u16* yb = ybuf + ((size_t)(e * SEG + m0)) * 1024 + n0 + wn * 64 + lrow;
#pragma unroll
  for (int mt = 0; mt < 4; ++mt) {
#pragma unroll
    for (int r = 0; r < 4; ++r) {
      int ml = wm * 64 + mt * 16 + rq * 4 + r;
      u16* row = yb + (size_t)ml * 1024;
#pragma unroll
      for (int nt = 0; nt < 4; ++nt)
        __builtin_nontemporal_store(f32_to_bf16(acc[mt][nt][r] + bias[nt]),
                                    &row[nt * 16]);
    }
  }
}

// ---------------------------------------------------------------------------
// Kernel 3: combine. out[t] = w0*ybuf[idx0] + w1*ybuf[idx1]  (pure BW).
// out is never re-read -> nontemporal stores.
// ---------------------------------------------------------------------------
__global__ __launch_bounds__(256) void combine_kernel(
    const u16* __restrict__ ybuf, const int* __restrict__ revIdx,
    const float* __restrict__ revW, float* __restrict__ out) {
  int tid = threadIdx.x, lane = tid & 63, wv = tid >> 6;
  for (int it = 0; it < 4; ++it) {
    int t  = blockIdx.x * 16 + wv * 4 + it;
    int i0 = revIdx[t * 2], i1 = revIdx[t * 2 + 1];
    float w0 = revW[t * 2], w1 = revW[t * 2 + 1];
    float o[16];
#pragma unroll
    for (int k = 0; k < 16; ++k) o[k] = 0.f;
    if (i0 >= 0) {
      const u16x8* y = (const u16x8*)(ybuf + (size_t)i0 * 1024);
#pragma unroll
      for (int jj = 0; jj < 2; ++jj) {
        u16x8 v = y[lane + 64 * jj];
#pragma unroll
        for (int k = 0; k < 8; ++k) o[jj * 8 + k] += w0 * bf16_to_f32(v[k]);
      }
    }
    if (i1 >= 0) {
      const u16x8* y = (const u16x8*)(ybuf + (size_t)i1 * 1024);
#pragma unroll
      for (int jj = 0; jj < 2; ++jj) {
        u16x8 v = y[lane + 64 * jj];
#pragma unroll
        for (int k = 0; k < 8; ++k) o[jj * 8 + k] += w1 * bf16_to_f32(v[k]);
      }
    }
    f32x4* o4 = (f32x4*)(out + (size_t)t * 1024);
#pragma unroll
    for (int jj = 0; jj < 2; ++jj)
#pragma unroll
      for (int h = 0; h < 2; ++h) {
        f32x4 vv = {o[jj * 8 + h * 4], o[jj * 8 + h * 4 + 1],
                    o[jj * 8 + h * 4 + 2], o[jj * 8 + h * 4 + 3]};
        __builtin_nontemporal_store(vv, &o4[2 * (lane + 64 * jj) + h]);
      }
  }
}

// ---------------------------------------------------------------------------
// Workspace layout (bytes), total ~64.2 MiB:
//   [0, 4096)        : int cnt[8*32] (one counter per 128B line)
//   [4096, +64K)     : tokList  8*2048 int (combined per-expert lists)
//   [+64K)           : revIdx   8192*2 int
//   [+64K)           : revW     8192*2 float
//   [+16M)           : xb   bf16 [8192][1024]
//   [+16M)           : wT   bf16 [8][1024][1024]
//   [+33.5M)         : ybuf bf16 [8*2048][1024]
// ---------------------------------------------------------------------------
extern "C" void kernel_launch(void* const* d_in, const int* in_sizes, int n_in,
                              void* d_out, int out_size, void* d_ws, size_t ws_size,
                              hipStream_t stream) {
  const float* x  = (const float*)d_in[0];
  const float* gw = (const float*)d_in[1];
  const float* gb = (const float*)d_in[2];
  const float* ew = (const float*)d_in[3];
  const float* eb = (const float*)d_in[4];
  float* out = (float*)d_out;
  char* ws = (char*)d_ws;
  int*   cnt     = (int*)ws;
  int*   tokList = (int*)(ws + 4096);
  int*   revIdx  = (int*)(ws + 4096 + 65536);
  float* revW    = (float*)(ws + 4096 + 131072);
  u16*   xb      = (u16*)(ws + 200704);
  u16*   wT      = (u16*)(ws + 200704 + 16777216);
  u16*   ybuf    = (u16*)(ws + 200704 + 33554432);

  hipMemsetAsync(cnt, 0, 4096, stream);
  prep_kernel<<<2560, 256, 0, stream>>>(x, gw, gb, ew, xb, wT, cnt, tokList,
                                        revIdx, revW);
  moe_gemm<<<dim3(8, 8, 16), 256, 0, stream>>>(xb, wT, cnt, tokList, eb, ybuf);
  combine_kernel<<<512, 256, 0, stream>>>(ybuf, revIdx, revW, out);
}